// Round 5
// baseline (438.730 us; speedup 1.0000x reference)
//
#include <hip/hip_runtime.h>

// Problem constants (from reference setup_inputs)
#define B_   4
#define H_   64
#define W_   2650
#define C_   64
#define N_   680000
#define THR_ 0.5f
#define HW_  (H_ * W_)          // 169600
#define W16_ 166                // ceil(W/16): 64B-line columns
#define M2_  (B_ * H_ * W16_)   // 42496 line-bins == 166 * 256 exactly
#define NB2_ (M2_ / 256)        // 166 scan blocks
#define SPR_ 21                 // strips per (b,r) row: ceil(166/8), strip = 128 cols
#define NSTRIP_ (B_ * H_ * SPR_)  // 5376 gather blocks
#define ROWF_ 129               // LDS row stride (floats). ODD -> inner read is
                                // (ch + x) % 32 across 64 lanes = 2-way = free.
#define NROWBLK_ (N_ / 64)      // 10625 bgzero blocks (64 rows each, exact)

// ---- counting-sort by (b, r, c>>4), FOREGROUND POINTS ONLY ---------------
// Background rows are zeroed by a STREAMING HOLE-SKIPPING pass (bgzero):
// pt-ordered, wave-coalesced dword writes that skip fg rows. This removes
// the 95 MB of wasted zero-writes to fg rows that the old full pre-zero did
// (fg rows are fully rewritten by gather anyway). Writes stay monotone ->
// DRAM row-buffer friendly, unlike per-point scattered zeroing.

__global__ void zero_bin_kernel(int* __restrict__ p) {
    p[blockIdx.x * 256 + threadIdx.x] = 0;               // grid == NB2_
}

// One block per 64 consecutive point rows. Wave 0 computes the 64 fg flags
// (ri contiguous, seg L2-resident, pts col0 line-sparse) -> ballot mask;
// then all 256 threads sweep the block's 64*69 = 4416 contiguous dwords,
// writing 0.0f only where the dword's row is background.
__global__ __launch_bounds__(256) void bgzero_kernel(
    const float* __restrict__ pts, const int* __restrict__ ri,
    const float* __restrict__ seg,
    float* __restrict__ out, float* __restrict__ mask_out)
{
    __shared__ unsigned long long fgmask_lds;
    const int t    = threadIdx.x;
    const int row0 = blockIdx.x * 64;
    if (t < 64) {                                // wave 0 only
        const int row = row0 + t;
        const int b   = (int)pts[(size_t)row * 5];
        const int2 rc = ((const int2*)ri)[row];
        const bool fg = seg[(size_t)b * HW_ + rc.x * W_ + rc.y] >= THR_;
        const unsigned long long bm = __ballot(fg);
        if (t == 0) fgmask_lds = bm;
        if (!fg) mask_out[row] = 0.0f;           // fg mask written by gather
    }
    __syncthreads();
    const unsigned long long m = fgmask_lds;
    const size_t base = (size_t)row0 * 69;
#pragma unroll
    for (int it = 0; it < 18; ++it) {            // 18*256 = 4608 >= 4416
        const int d = it * 256 + t;
        if (d >= 4416) break;
        const int row = (unsigned)d / 69u;       // const divisor -> magic mul
        if (!((m >> row) & 1ULL)) out[base + d] = 0.0f;
    }
}

__global__ void hist_kernel(const float* __restrict__ pts,
                            const int* __restrict__ ri,
                            const float* __restrict__ seg,
                            int* __restrict__ binarr) {
    int i = blockIdx.x * 256 + threadIdx.x;
    if (i >= N_) return;
    int b = (int)pts[(size_t)i * 5];
    int2 rc = ((const int2*)ri)[i];
    if (seg[(size_t)b * HW_ + rc.x * W_ + rc.y] >= THR_)  // fg only
        atomicAdd(&binarr[(b * H_ + rc.x) * W16_ + (rc.y >> 4)], 1);
}

// 3-kernel parallel scan (1-block fused variant serialized the graph, +30µs).
__global__ void scan1_kernel(int* __restrict__ binarr, int* __restrict__ bsum) {
    __shared__ int lds[256];
    int t = threadIdx.x;
    int g = blockIdx.x * 256 + t;
    int v = binarr[g];
    lds[t] = v;
    __syncthreads();
    for (int off = 1; off < 256; off <<= 1) {    // Hillis-Steele inclusive
        int x = (t >= off) ? lds[t - off] : 0;
        __syncthreads();
        lds[t] += x;
        __syncthreads();
    }
    binarr[g] = lds[t] - v;                      // exclusive, in place
    if (t == 255) bsum[blockIdx.x] = lds[255];
}

__global__ void scan2_kernel(int* __restrict__ bsum) {
    __shared__ int lds[256];
    int t = threadIdx.x;
    int v = (t < NB2_) ? bsum[t] : 0;
    lds[t] = v;
    __syncthreads();
    for (int off = 1; off < 256; off <<= 1) {
        int x = (t >= off) ? lds[t - off] : 0;
        __syncthreads();
        lds[t] += x;
        __syncthreads();
    }
    if (t < NB2_) bsum[t] = lds[t] - v;          // exclusive
}

__global__ void scan3_kernel(int* __restrict__ binarr, const int* __restrict__ bsum) {
    int g = blockIdx.x * 256 + threadIdx.x;      // grid == NB2_ blocks
    binarr[g] += bsum[blockIdx.x];
}

// Assign each FG point its sorted slot; pack {pt, c&127} (strip-local col).
__global__ void scatter_kernel(const float* __restrict__ pts,
                               const int* __restrict__ ri,
                               const float* __restrict__ seg,
                               int* __restrict__ binarr,
                               int* __restrict__ perm) {
    int i = blockIdx.x * 256 + threadIdx.x;
    if (i >= N_) return;
    int b   = (int)pts[(size_t)i * 5];
    int2 rc = ((const int2*)ri)[i];
    int r = rc.x, c = rc.y;
    if (seg[(size_t)b * HW_ + r * W_ + c] < THR_) return;   // fg only
    int bin  = (b * H_ + r) * W16_ + (c >> 4);
    int slot = atomicAdd(&binarr[bin], 1);
    perm[slot] = i | ((c & 127) << 20);          // N < 2^20, col in bits 20..26
}

// ---- main gather: one BLOCK per 128-col strip (8 bins) -------------------
// Staging: 64 ch x 512B contiguous per channel (float2, fully coalesced).
// LDS row stride 129 floats (odd): inner read bank = (ch + x) % 32 -> 2-way,
// free. 4 waves split the strip's fg-point range; per-wave perm chunks
// (<=64) fetched coalesced + broadcast via __shfl; attrs staged
// cooperatively so the inner loop has no dependent global loads.
__global__ __launch_bounds__(256) void gather_kernel(
    const float* __restrict__ pts,       // [N,5]
    const float* __restrict__ feat,      // [B,C,H,W]
    const int*   __restrict__ binarr,    // [M2_] post-scatter inclusive ends
    const int*   __restrict__ perm,      // [Nfg] packed records
    float* __restrict__ out,             // [N,69] (bg rows zeroed by bgzero)
    float* __restrict__ mask_out)        // [N]    (bg rows zeroed by bgzero)
{
    __shared__ float flds[64 * ROWF_];   // 33 KB feature strip
    __shared__ float alds[4][64 * 5];    // per-wave staged point attrs
    const int t    = threadIdx.x;
    const int lane = t & 63;
    const int w    = t >> 6;

    const int sx  = blockIdx.x % SPR_;
    const int tmp = blockIdx.x / SPR_;
    const int r   = tmp & (H_ - 1);
    const int b   = tmp >> 6;

    const int rowbin  = (b * H_ + r) * W16_;
    const int first   = rowbin + sx * 8;
    const int lastbin = rowbin + min(sx * 8 + 8, W16_) - 1;
    const int start   = (first == 0) ? 0 : binarr[first - 1];
    const int end     = binarr[lastbin];
    if (start == end) return;                    // block-uniform

    // per-wave contiguous sub-range of the strip's points
    const int tot = end - start;
    const int q = tot >> 2, rm = tot & 3;
    const int wstart = start + w * q + min(w, rm);
    const int wend   = wstart + q + (w < rm ? 1 : 0);

    // Issue first perm chunk BEFORE staging: latencies overlap.
    int cnt = min(wend - wstart, 64);            // may be 0 for tail waves
    int rec_l = (lane < cnt) ? perm[wstart + lane] : 0;

    // ---- block-cooperative feature staging: 64ch x 128 cols = 32 KB ------
    const int c0 = sx * 128;
    if (c0 + 128 <= W_) {
#pragma unroll
        for (int g = 0; g < 16; g++) {
            const int ch = 4 * g + w;            // each (g,wave) a unique ch
            const int x  = 2 * (lane);           // 0..126, even
            // r*W_, c0, x all even -> 8B-aligned float2
            const float2 v = *(const float2*)(feat + (size_t)(b * C_ + ch) * HW_
                                              + (size_t)r * W_ + c0 + x);
            flds[ch * ROWF_ + x]     = v.x;      // bank (ch+2l)%32: 2-way, free
            flds[ch * ROWF_ + x + 1] = v.y;
        }
    } else {                                     // edge strip (sx==20): clamp
#pragma unroll
        for (int g = 0; g < 16; g++) {
            const int ch = 4 * g + w;
            const int x  = 2 * (lane);
            int c1 = c0 + x;     if (c1 >= W_) c1 = W_ - 1;
            int c2 = c0 + x + 1; if (c2 >= W_) c2 = W_ - 1;
            const size_t base = (size_t)(b * C_ + ch) * HW_ + (size_t)r * W_;
            flds[ch * ROWF_ + x]     = feat[base + c1];
            flds[ch * ROWF_ + x + 1] = feat[base + c2];
        }
    }
    __syncthreads();
    if (wstart >= wend) return;                  // tail waves done after staging

    float* arow = alds[w];
    const float* myrow = &flds[lane * ROWF_];    // lane == channel
    int p0 = wstart;
    for (;;) {
        // Cooperative attr staging: cnt*5 floats, all lanes load in parallel.
        // __shfl executed by ALL lanes (uniform bound), store predicated,
        // source index clamped into [0,cnt) so only live lanes are read.
        const int na = cnt * 5;
        for (int rbase = 0; rbase < na; rbase += 64) {
            int idx = rbase + lane;
            int pj  = idx / 5;                   // magic-mul, no div unit
            int a   = idx - pj * 5;
            int pjc = (idx < na) ? pj : 0;
            int ptj = __shfl(rec_l, pjc) & 0xFFFFF;
            if (idx < na) arow[idx] = pts[(size_t)ptj * 5 + a];
        }
        // single-wave producer/consumer on arow: compiler waitcnts suffice
#pragma unroll 4
        for (int j = 0; j < cnt; j++) {
            const int rec = __shfl(rec_l, j);    // broadcast, no memory
            const int pt  = rec & 0xFFFFF;
            const float f = myrow[(rec >> 20) & 127];
            const size_t orow = (size_t)pt * 69;
            out[orow + 5 + lane] = f;            // 256 B contiguous store
            if (lane < 5) out[orow + lane] = arow[j * 5 + lane];
            if (lane == 0) mask_out[pt] = 1.0f;
        }
        p0 += cnt;
        if (p0 >= wend) break;
        cnt = min(wend - p0, 64);
        rec_l = (lane < cnt) ? perm[p0 + lane] : 0;
    }
}

// ---- fallback (identity order) — only if ws too small. Writes ALL rows. --
__global__ __launch_bounds__(256) void gather_fallback(
    const float* __restrict__ pts, const int* __restrict__ ri,
    const float* __restrict__ seg, const float* __restrict__ feat,
    float* __restrict__ out, float* __restrict__ mask_out)
{
    const int lane = threadIdx.x & 63;
    const int pt   = blockIdx.x * 4 + (threadIdx.x >> 6);
    if (pt >= N_) return;
    int b = (int)pts[(size_t)pt * 5];
    int r = ri[pt * 2], c = ri[pt * 2 + 1];
    int rc = r * W_ + c;
    float m = (seg[b * HW_ + rc] >= THR_) ? 1.0f : 0.0f;
    float f = feat[(size_t)b * (C_ * HW_) + (size_t)lane * HW_ + rc];
    size_t orow = (size_t)pt * 69;
    out[orow + 5 + lane] = f * m;
    if (lane < 5) out[orow + lane] = pts[(size_t)pt * 5 + lane] * m;
    if (lane == 0) mask_out[pt] = m;
}

// ---- launch --------------------------------------------------------------

extern "C" void kernel_launch(void* const* d_in, const int* in_sizes, int n_in,
                              void* d_out, int out_size, void* d_ws, size_t ws_size,
                              hipStream_t stream) {
    const float* points = (const float*)d_in[0];
    const int*   ri     = (const int*)  d_in[1];
    const float* seg    = (const float*)d_in[2];
    const float* feat   = (const float*)d_in[3];

    float* out      = (float*)d_out;                       // N*69
    float* mask_out = (float*)d_out + (size_t)N_ * 69;     // N (contiguous)

    // Workspace layout (ints): binarr[M2_] | bsum[256] | perm[N_]  ~2.9 MB
    int* binarr = (int*)d_ws;
    int* bsum   = binarr + M2_;
    int* perm   = bsum + 256;
    const size_t needed = ((size_t)M2_ + 256 + N_) * sizeof(int);
    const bool use_sort = (ws_size >= needed);   // ws_size constant -> replay-safe

    const int nblkN = (N_ + 255) / 256;

    if (use_sort) {
        zero_bin_kernel<<<NB2_,    256, 0, stream>>>(binarr);
        hist_kernel    <<<nblkN,   256, 0, stream>>>(points, ri, seg, binarr);
        scan1_kernel   <<<NB2_,    256, 0, stream>>>(binarr, bsum);
        scan2_kernel   <<<1,       256, 0, stream>>>(bsum);
        scan3_kernel   <<<NB2_,    256, 0, stream>>>(binarr, bsum);
        scatter_kernel <<<nblkN,   256, 0, stream>>>(points, ri, seg, binarr, perm);
        bgzero_kernel  <<<NROWBLK_, 256, 0, stream>>>(points, ri, seg, out, mask_out);
        gather_kernel  <<<NSTRIP_, 256, 0, stream>>>(points, feat, binarr, perm,
                                                     out, mask_out);
    } else {
        gather_fallback<<<(N_ + 3) / 4, 256, 0, stream>>>(points, ri, seg, feat,
                                                          out, mask_out);
    }
}

// Round 6
// 403.885 us; speedup vs baseline: 1.0863x; 1.0863x over previous
//
#include <hip/hip_runtime.h>

// Problem constants (from reference setup_inputs)
#define B_   4
#define H_   64
#define W_   2650
#define C_   64
#define N_   680000
#define THR_ 0.5f
#define HW_  (H_ * W_)          // 169600
#define W16_ 166                // ceil(W/16): 64B-line columns
#define M2_  (B_ * H_ * W16_)   // 42496 line-bins == 166 * 256 exactly
#define NB2_ (M2_ / 256)        // 166 scan blocks
#define SPR_ 21                 // strips per (b,r) row: ceil(166/8), strip = 128 cols
#define NSTRIP_ (B_ * H_ * SPR_)  // 5376 gather blocks
#define ROWF_ 129               // LDS row stride (floats). ODD -> inner read is
                                // (ch + x) % 32 across 64 lanes = 2-way = free.

// R5 lesson: dense streaming zero beats hole-skipping zero even at 2x bytes
// (predicated holey stores break coalescing; +21 us). Reverted to dense zero,
// now FUSED into hist (write-bound sweep overlaps hist's latency-bound
// atomics). scan3 folded into scatter/gather via bsum add. Point attrs ride
// in the perm record (24B) so gather never randomly touches pts.

__global__ void zero_bin_kernel(int* __restrict__ p) {
    p[blockIdx.x * 256 + threadIdx.x] = 0;               // grid == NB2_
}

// hist + streaming zero of out/mask (N*70 floats). The zero sweep is
// write-bound (~30us); hist's scattered reads+atomics hide under it.
__global__ __launch_bounds__(256) void hist_zero_kernel(
    const float* __restrict__ pts, const int* __restrict__ ri,
    const float* __restrict__ seg,
    int* __restrict__ binarr, float4* __restrict__ outz)
{
    const int i = blockIdx.x * 256 + threadIdx.x;
    if (i < N_) {
        int b = (int)pts[(size_t)i * 5];
        int2 rc = ((const int2*)ri)[i];
        if (seg[(size_t)b * HW_ + rc.x * W_ + rc.y] >= THR_)      // fg only
            atomicAdd(&binarr[(b * H_ + rc.x) * W16_ + (rc.y >> 4)], 1);
    }
    const size_t total  = (size_t)N_ * 70 / 4;           // 11.9M float4, exact
    const size_t stride = (size_t)gridDim.x * 256;
    const float4 z = {0.f, 0.f, 0.f, 0.f};
    for (size_t idx = (size_t)blockIdx.x * 256 + threadIdx.x; idx < total;
         idx += stride)
        outz[idx] = z;
}

// Per-256-block exclusive scan; block totals -> bsum. (Global offsets are
// applied later as binarr[g] + bsum[g>>8]; no scan3 pass.)
__global__ void scan1_kernel(int* __restrict__ binarr, int* __restrict__ bsum) {
    __shared__ int lds[256];
    int t = threadIdx.x;
    int g = blockIdx.x * 256 + t;
    int v = binarr[g];
    lds[t] = v;
    __syncthreads();
    for (int off = 1; off < 256; off <<= 1) {    // Hillis-Steele inclusive
        int x = (t >= off) ? lds[t - off] : 0;
        __syncthreads();
        lds[t] += x;
        __syncthreads();
    }
    binarr[g] = lds[t] - v;                      // block-local exclusive
    if (t == 255) bsum[blockIdx.x] = lds[255];
}

__global__ void scan2_kernel(int* __restrict__ bsum) {
    __shared__ int lds[256];
    int t = threadIdx.x;
    int v = (t < NB2_) ? bsum[t] : 0;
    lds[t] = v;
    __syncthreads();
    for (int off = 1; off < 256; off <<= 1) {
        int x = (t >= off) ? lds[t - off] : 0;
        __syncthreads();
        lds[t] += x;
        __syncthreads();
    }
    if (t < NB2_) bsum[t] = lds[t] - v;          // exclusive
}

// ---- AP path: scatter writes 24B records {rec, 5 attrs} ------------------
// pts lines are touched for col0 anyway, so reading all 5 attrs is free;
// gather then reads records coalesced and never touches pts.
__global__ void scatter_ap_kernel(const float* __restrict__ pts,
                                  const int* __restrict__ ri,
                                  const float* __restrict__ seg,
                                  int* __restrict__ binarr,
                                  const int* __restrict__ bsum,
                                  int* __restrict__ aperm) {
    int i = blockIdx.x * 256 + threadIdx.x;
    if (i >= N_) return;
    const float* pr = pts + (size_t)i * 5;
    float a0 = pr[0], a1 = pr[1], a2 = pr[2], a3 = pr[3], a4 = pr[4];
    int b = (int)a0;
    int2 rc = ((const int2*)ri)[i];
    int r = rc.x, c = rc.y;
    if (seg[(size_t)b * HW_ + r * W_ + c] < THR_) return;   // fg only
    int bin  = (b * H_ + r) * W16_ + (c >> 4);
    int slot = atomicAdd(&binarr[bin], 1) + bsum[bin >> 8];
    int rec  = i | ((c & 127) << 20);            // N < 2^20, col in 20..26
    int2* A2 = (int2*)aperm + (size_t)slot * 3;  // slot*24 B, 8B-aligned
    A2[0] = make_int2(rec, __float_as_int(a0));
    A2[1] = make_int2(__float_as_int(a1), __float_as_int(a2));
    A2[2] = make_int2(__float_as_int(a3), __float_as_int(a4));
}

// ---- MID path (R4-equivalent, if ws too small for aperm) -----------------
__global__ void scatter_mid_kernel(const float* __restrict__ pts,
                                   const int* __restrict__ ri,
                                   const float* __restrict__ seg,
                                   int* __restrict__ binarr,
                                   const int* __restrict__ bsum,
                                   int* __restrict__ perm) {
    int i = blockIdx.x * 256 + threadIdx.x;
    if (i >= N_) return;
    int b   = (int)pts[(size_t)i * 5];
    int2 rc = ((const int2*)ri)[i];
    int r = rc.x, c = rc.y;
    if (seg[(size_t)b * HW_ + r * W_ + c] < THR_) return;
    int bin  = (b * H_ + r) * W16_ + (c >> 4);
    int slot = atomicAdd(&binarr[bin], 1) + bsum[bin >> 8];
    perm[slot] = i | ((c & 127) << 20);
}

// ---- main gather (AP): one BLOCK per 128-col strip (8 bins) --------------
// Staging: 64 ch x 512B contiguous per channel (float2, fully coalesced).
// LDS row stride 129 (odd) -> inner read 2 lanes/bank, free. 4 waves split
// the strip's fg range; 24B records fetched coalesced (lane j takes record
// j: 3x int2, wave covers contiguous 1536B), next chunk prefetched under
// the store loop; attrs staged to LDS (stride 5, odd -> 2-way, free).
__global__ __launch_bounds__(256) void gather_ap_kernel(
    const float* __restrict__ feat,      // [B,C,H,W]
    const int*   __restrict__ binarr,    // block-local inclusive ends
    const int*   __restrict__ bsum,      // per-block exclusive offsets
    const int*   __restrict__ aperm,     // [Nfg] 24B records
    float* __restrict__ out,             // [N,69] (bg pre-zeroed)
    float* __restrict__ mask_out)        // [N]    (bg pre-zeroed)
{
    __shared__ float flds[64 * ROWF_];   // 33 KB feature strip
    __shared__ float alds[4][64 * 5];    // per-wave staged point attrs
    const int t    = threadIdx.x;
    const int lane = t & 63;
    const int w    = t >> 6;

    const int sx  = blockIdx.x % SPR_;
    const int tmp = blockIdx.x / SPR_;
    const int r   = tmp & (H_ - 1);
    const int b   = tmp >> 6;

    const int rowbin  = (b * H_ + r) * W16_;
    const int first   = rowbin + sx * 8;
    const int lastbin = rowbin + min(sx * 8 + 8, W16_) - 1;
    const int start   = (first == 0) ? 0
                        : binarr[first - 1] + bsum[(first - 1) >> 8];
    const int end     = binarr[lastbin] + bsum[lastbin >> 8];
    if (start == end) return;                    // block-uniform

    // per-wave contiguous sub-range of the strip's points
    const int tot = end - start;
    const int q = tot >> 2, rm = tot & 3;
    const int wstart = start + w * q + min(w, rm);
    const int wend   = wstart + q + (w < rm ? 1 : 0);

    // Issue first record chunk BEFORE staging: latencies overlap.
    const int2* A2 = (const int2*)aperm;
    int cnt = min(wend - wstart, 64);            // may be 0 for tail waves
    int2 q0 = {0, 0}, q1 = {0, 0}, q2 = {0, 0};
    if (lane < cnt) {
        size_t rb = (size_t)(wstart + lane) * 3;
        q0 = A2[rb]; q1 = A2[rb + 1]; q2 = A2[rb + 2];
    }

    // ---- block-cooperative feature staging: 64ch x 128 cols = 32 KB ------
    const int c0 = sx * 128;
    if (c0 + 128 <= W_) {
#pragma unroll
        for (int g = 0; g < 16; g++) {
            const int ch = 4 * g + w;            // each (g,wave) a unique ch
            const int x  = 2 * lane;             // 0..126, even
            const float2 v = *(const float2*)(feat + (size_t)(b * C_ + ch) * HW_
                                              + (size_t)r * W_ + c0 + x);
            flds[ch * ROWF_ + x]     = v.x;      // bank (ch+2l)%32: 2-way, free
            flds[ch * ROWF_ + x + 1] = v.y;
        }
    } else {                                     // edge strip (sx==20): clamp
#pragma unroll
        for (int g = 0; g < 16; g++) {
            const int ch = 4 * g + w;
            const int x  = 2 * lane;
            int c1 = c0 + x;     if (c1 >= W_) c1 = W_ - 1;
            int c2 = c0 + x + 1; if (c2 >= W_) c2 = W_ - 1;
            const size_t base = (size_t)(b * C_ + ch) * HW_ + (size_t)r * W_;
            flds[ch * ROWF_ + x]     = feat[base + c1];
            flds[ch * ROWF_ + x + 1] = feat[base + c2];
        }
    }
    __syncthreads();
    if (wstart >= wend) return;                  // tail waves done after staging

    float* arow = alds[w];
    const float* myrow = &flds[lane * ROWF_];    // lane == channel
    int p0 = wstart;
    for (;;) {
        // stage this chunk's attrs to LDS (lane j -> arow[j*5..j*5+4])
        if (lane < cnt) {
            float* d = &arow[lane * 5];
            d[0] = __int_as_float(q0.y);
            d[1] = __int_as_float(q1.x);
            d[2] = __int_as_float(q1.y);
            d[3] = __int_as_float(q2.x);
            d[4] = __int_as_float(q2.y);
        }
        const int rl0 = q0.x;
        // prefetch next chunk's records under the store loop
        const int ncnt = min(wend - (p0 + cnt), 64);
        q0 = make_int2(0, 0); q1 = make_int2(0, 0); q2 = make_int2(0, 0);
        if (lane < ncnt) {
            size_t rb = (size_t)(p0 + cnt + lane) * 3;
            q0 = A2[rb]; q1 = A2[rb + 1]; q2 = A2[rb + 2];
        }
#pragma unroll 4
        for (int j = 0; j < cnt; j++) {
            const int rec = __shfl(rl0, j);      // broadcast, no memory
            const int pt  = rec & 0xFFFFF;
            const float f = myrow[(rec >> 20) & 127];
            const size_t orow = (size_t)pt * 69;
            out[orow + 5 + lane] = f;            // 256 B contiguous store
            if (lane < 5) out[orow + lane] = arow[j * 5 + lane];
            if (lane == 0) mask_out[pt] = 1.0f;
        }
        p0 += cnt;
        if (p0 >= wend) break;
        cnt = ncnt;
    }
}

// ---- mid gather (R4 structure + bsum add), if ws too small for aperm -----
__global__ __launch_bounds__(256) void gather_mid_kernel(
    const float* __restrict__ pts, const float* __restrict__ feat,
    const int* __restrict__ binarr, const int* __restrict__ bsum,
    const int* __restrict__ perm,
    float* __restrict__ out, float* __restrict__ mask_out)
{
    __shared__ float flds[64 * ROWF_];
    __shared__ float alds[4][64 * 5];
    const int t    = threadIdx.x;
    const int lane = t & 63;
    const int w    = t >> 6;

    const int sx  = blockIdx.x % SPR_;
    const int tmp = blockIdx.x / SPR_;
    const int r   = tmp & (H_ - 1);
    const int b   = tmp >> 6;

    const int rowbin  = (b * H_ + r) * W16_;
    const int first   = rowbin + sx * 8;
    const int lastbin = rowbin + min(sx * 8 + 8, W16_) - 1;
    const int start   = (first == 0) ? 0
                        : binarr[first - 1] + bsum[(first - 1) >> 8];
    const int end     = binarr[lastbin] + bsum[lastbin >> 8];
    if (start == end) return;

    const int tot = end - start;
    const int q = tot >> 2, rm = tot & 3;
    const int wstart = start + w * q + min(w, rm);
    const int wend   = wstart + q + (w < rm ? 1 : 0);

    int cnt = min(wend - wstart, 64);
    int rec_l = (lane < cnt) ? perm[wstart + lane] : 0;

    const int c0 = sx * 128;
    if (c0 + 128 <= W_) {
#pragma unroll
        for (int g = 0; g < 16; g++) {
            const int ch = 4 * g + w;
            const int x  = 2 * lane;
            const float2 v = *(const float2*)(feat + (size_t)(b * C_ + ch) * HW_
                                              + (size_t)r * W_ + c0 + x);
            flds[ch * ROWF_ + x]     = v.x;
            flds[ch * ROWF_ + x + 1] = v.y;
        }
    } else {
#pragma unroll
        for (int g = 0; g < 16; g++) {
            const int ch = 4 * g + w;
            const int x  = 2 * lane;
            int c1 = c0 + x;     if (c1 >= W_) c1 = W_ - 1;
            int c2 = c0 + x + 1; if (c2 >= W_) c2 = W_ - 1;
            const size_t base = (size_t)(b * C_ + ch) * HW_ + (size_t)r * W_;
            flds[ch * ROWF_ + x]     = feat[base + c1];
            flds[ch * ROWF_ + x + 1] = feat[base + c2];
        }
    }
    __syncthreads();
    if (wstart >= wend) return;

    float* arow = alds[w];
    const float* myrow = &flds[lane * ROWF_];
    int p0 = wstart;
    for (;;) {
        const int na = cnt * 5;
        for (int rbase = 0; rbase < na; rbase += 64) {
            int idx = rbase + lane;
            int pj  = idx / 5;
            int a   = idx - pj * 5;
            int pjc = (idx < na) ? pj : 0;
            int ptj = __shfl(rec_l, pjc) & 0xFFFFF;
            if (idx < na) arow[idx] = pts[(size_t)ptj * 5 + a];
        }
#pragma unroll 4
        for (int j = 0; j < cnt; j++) {
            const int rec = __shfl(rec_l, j);
            const int pt  = rec & 0xFFFFF;
            const float f = myrow[(rec >> 20) & 127];
            const size_t orow = (size_t)pt * 69;
            out[orow + 5 + lane] = f;
            if (lane < 5) out[orow + lane] = arow[j * 5 + lane];
            if (lane == 0) mask_out[pt] = 1.0f;
        }
        p0 += cnt;
        if (p0 >= wend) break;
        cnt = min(wend - p0, 64);
        rec_l = (lane < cnt) ? perm[p0 + lane] : 0;
    }
}

// ---- fallback (identity order) — only if ws too small. Writes ALL rows. --
__global__ __launch_bounds__(256) void gather_fallback(
    const float* __restrict__ pts, const int* __restrict__ ri,
    const float* __restrict__ seg, const float* __restrict__ feat,
    float* __restrict__ out, float* __restrict__ mask_out)
{
    const int lane = threadIdx.x & 63;
    const int pt   = blockIdx.x * 4 + (threadIdx.x >> 6);
    if (pt >= N_) return;
    int b = (int)pts[(size_t)pt * 5];
    int r = ri[pt * 2], c = ri[pt * 2 + 1];
    int rc = r * W_ + c;
    float m = (seg[b * HW_ + rc] >= THR_) ? 1.0f : 0.0f;
    float f = feat[(size_t)b * (C_ * HW_) + (size_t)lane * HW_ + rc];
    size_t orow = (size_t)pt * 69;
    out[orow + 5 + lane] = f * m;
    if (lane < 5) out[orow + lane] = pts[(size_t)pt * 5 + lane] * m;
    if (lane == 0) mask_out[pt] = m;
}

// ---- launch --------------------------------------------------------------

extern "C" void kernel_launch(void* const* d_in, const int* in_sizes, int n_in,
                              void* d_out, int out_size, void* d_ws, size_t ws_size,
                              hipStream_t stream) {
    const float* points = (const float*)d_in[0];
    const int*   ri     = (const int*)  d_in[1];
    const float* seg    = (const float*)d_in[2];
    const float* feat   = (const float*)d_in[3];

    float* out      = (float*)d_out;                       // N*69
    float* mask_out = (float*)d_out + (size_t)N_ * 69;     // N (contiguous)

    // Workspace (ints): binarr[M2_] | bsum[256] | aperm[N*6]  ~15.8 MB (AP)
    //               or: binarr[M2_] | bsum[256] | perm[N]      ~2.9 MB (MID)
    int* binarr = (int*)d_ws;
    int* bsum   = binarr + M2_;
    int* payload = bsum + 256;
    const size_t need_ap  = ((size_t)M2_ + 256 + (size_t)N_ * 6) * sizeof(int);
    const size_t need_mid = ((size_t)M2_ + 256 + N_) * sizeof(int);

    const int nblkN = (N_ + 255) / 256;

    if (ws_size >= need_ap) {
        zero_bin_kernel<<<NB2_,   256, 0, stream>>>(binarr);
        hist_zero_kernel<<<nblkN, 256, 0, stream>>>(points, ri, seg, binarr,
                                                    (float4*)out);
        scan1_kernel   <<<NB2_,   256, 0, stream>>>(binarr, bsum);
        scan2_kernel   <<<1,      256, 0, stream>>>(bsum);
        scatter_ap_kernel<<<nblkN, 256, 0, stream>>>(points, ri, seg, binarr,
                                                     bsum, payload);
        gather_ap_kernel<<<NSTRIP_, 256, 0, stream>>>(feat, binarr, bsum,
                                                      payload, out, mask_out);
    } else if (ws_size >= need_mid) {
        zero_bin_kernel<<<NB2_,   256, 0, stream>>>(binarr);
        hist_zero_kernel<<<nblkN, 256, 0, stream>>>(points, ri, seg, binarr,
                                                    (float4*)out);
        scan1_kernel   <<<NB2_,   256, 0, stream>>>(binarr, bsum);
        scan2_kernel   <<<1,      256, 0, stream>>>(bsum);
        scatter_mid_kernel<<<nblkN, 256, 0, stream>>>(points, ri, seg, binarr,
                                                      bsum, payload);
        gather_mid_kernel<<<NSTRIP_, 256, 0, stream>>>(points, feat, binarr,
                                                       bsum, payload, out,
                                                       mask_out);
    } else {
        gather_fallback<<<(N_ + 3) / 4, 256, 0, stream>>>(points, ri, seg, feat,
                                                          out, mask_out);
    }
}